// Round 8
// baseline (400.490 us; speedup 1.0000x reference)
//
#include <hip/hip_runtime.h>

#define IN_DIM 23
#define HID 128
#define OUTD 64
#define NGR 64
#define NPART 32
#define FILL_GRP 8
#define FB_DIM 32    // feat padded to 32 bf16 = 64B aligned rows
#define PH_STRIDE 136  // 16 rows x 136 bf16: 272B row stride (16B-aligned, bank-spread)

typedef __attribute__((ext_vector_type(8))) short bf16x8;
typedef __attribute__((ext_vector_type(4))) float f32x4;
typedef __attribute__((ext_vector_type(2))) float f32x2;

static __device__ __forceinline__ unsigned short f2bf(float x) {
    unsigned u = __float_as_uint(x);
    unsigned r = (u + 0x7FFFu + ((u >> 16) & 1u)) >> 16;   // RNE
    return (unsigned short)r;
}
static __device__ __forceinline__ float bf2f(unsigned short u) {
    return __uint_as_float((unsigned)u << 16);             // exact
}

// ---- fp8 e4m3 (OCP) encode: RNE, satfinite. Used only in transcode kernel. --
static __device__ __forceinline__ unsigned enc_fp8(float x) {
    float a = fabsf(x);
    unsigned s = (__float_as_uint(x) >> 31) << 7;
    if (!(a > 0.f)) return s;                    // zero
    a = fminf(a, 448.f);
    int eb; float fr = frexpf(a, &eb);           // a = fr*2^eb, fr in [0.5,1)
    int E = eb - 1;
    int code;
    if (E < -6) code = (int)rintf(ldexpf(a, 9)); // denormal: m = rint(a*2^9); m==8 -> 0x08 = 2^-6, correct
    else        code = ((E + 7) << 3) + (int)rintf(ldexpf(fr, 4)) - 8;  // mant overflow rolls E, correct
    code = min(code, 0x7E);
    return s | (unsigned)code;
}

// ---- fp8 e4m3 decode: HW packed convert if available, exact manual fallback -
#if __has_builtin(__builtin_amdgcn_cvt_pk_f32_fp8)
static __device__ __forceinline__ void dec4_fp8(unsigned u, float& d0, float& d1,
                                                float& d2, float& d3) {
    f32x2 lo = __builtin_amdgcn_cvt_pk_f32_fp8((int)u, false);
    f32x2 hi = __builtin_amdgcn_cvt_pk_f32_fp8((int)u, true);
    d0 = lo[0]; d1 = lo[1]; d2 = hi[0]; d3 = hi[1];
}
#else
static __device__ __forceinline__ float dec1_fp8(unsigned b) {
    unsigned s = (b & 0x80u) << 24;
    unsigned em = b & 0x7Fu;
    float f = __uint_as_float(s | ((em << 20) + 0x3C000000u));
    if ((b & 0x78u) == 0)   // denormal: true = 2f -/+ 2^-6
        f = 2.f * f - __uint_as_float(s | 0x3C800000u);
    return f;
}
static __device__ __forceinline__ void dec4_fp8(unsigned u, float& d0, float& d1,
                                                float& d2, float& d3) {
    d0 = dec1_fp8(u & 0xFF); d1 = dec1_fp8((u >> 8) & 0xFF);
    d2 = dec1_fp8((u >> 16) & 0xFF); d3 = dec1_fp8(u >> 24);
}
#endif

// ---------------- A: int degree histogram ------------------------------------
__global__ __launch_bounds__(256) void k_hist(
    const int* __restrict__ dst, int* __restrict__ degi, int n_edges)
{
    int e = blockIdx.x * 256 + threadIdx.x;
    if (e < n_edges) atomicAdd(&degi[dst[e]], 1);
}

// ---------------- A2: transcode feat0 -> bf16 padded rows --------------------
__global__ __launch_bounds__(256) void k_featb(
    const float* __restrict__ feat0, unsigned short* __restrict__ featb,
    int n_nodes)
{
    int i = blockIdx.x * 256 + threadIdx.x;
    if (i >= n_nodes * FB_DIM) return;
    int v = i >> 5, d = i & (FB_DIM - 1);
    float x = (d < IN_DIM) ? feat0[(size_t)v * IN_DIM + d] : 0.f;
    featb[i] = f2bf(x);
}

// ---------------- A3: weight transpose+pad to bf16 MFMA B-operand layout -----
__global__ __launch_bounds__(256) void k_wprep(
    const float* __restrict__ W1, const float* __restrict__ W2,
    unsigned short* __restrict__ W1t, unsigned short* __restrict__ W2t)
{
    int i = blockIdx.x * 256 + threadIdx.x;
    if (i < HID * 32) {
        int h = i >> 5, d = i & 31;
        W1t[i] = f2bf((d < IN_DIM) ? W1[d * HID + h] : 0.f);
    } else if (i < HID * 32 + OUTD * HID) {
        int j = i - HID * 32;
        int o = j >> 7, k = j & 127;
        W2t[j] = f2bf(W2[k * OUTD + o]);
    }
}

// ---------------- B1: per-block local exclusive scan + block totals ----------
__global__ __launch_bounds__(256) void k_scan_local(
    const int* __restrict__ degi, int* __restrict__ local,
    int* __restrict__ bsum, int n_nodes)
{
    int base = blockIdx.x * 1024 + threadIdx.x * 4;
    int4 d = {0, 0, 0, 0};
    if (base + 3 < n_nodes) {
        d = *(const int4*)&degi[base];
    } else {
        if (base + 0 < n_nodes) d.x = degi[base + 0];
        if (base + 1 < n_nodes) d.y = degi[base + 1];
        if (base + 2 < n_nodes) d.z = degi[base + 2];
        if (base + 3 < n_nodes) d.w = degi[base + 3];
    }
    int tsum = d.x + d.y + d.z + d.w;
    int lane = threadIdx.x & 63;
    int wave = threadIdx.x >> 6;
    int s = tsum;
#pragma unroll
    for (int off = 1; off < 64; off <<= 1) {
        int v = __shfl_up(s, off);
        if (lane >= off) s += v;
    }
    __shared__ int wtot[4];
    if (lane == 63) wtot[wave] = s;
    __syncthreads();
    int woff = 0;
#pragma unroll
    for (int i = 0; i < 4; ++i) woff += (i < wave) ? wtot[i] : 0;
    int excl = woff + s - tsum;
    int l0 = excl;
    int l1 = l0 + d.x;
    int l2 = l1 + d.y;
    int l3 = l2 + d.z;
    if (base + 3 < n_nodes) {
        *(int4*)&local[base] = make_int4(l0, l1, l2, l3);
    } else {
        if (base + 0 < n_nodes) local[base + 0] = l0;
        if (base + 1 < n_nodes) local[base + 1] = l1;
        if (base + 2 < n_nodes) local[base + 2] = l2;
        if (base + 3 < n_nodes) local[base + 3] = l3;
    }
    if (threadIdx.x == 255) bsum[blockIdx.x] = excl + tsum;
}

// ---------------- B2: scan the (<=1024) block totals -------------------------
__global__ __launch_bounds__(1024) void k_scan_bsum(
    const int* __restrict__ bsum, int* __restrict__ boff,
    int* __restrict__ rowstart, int nb, int n_nodes, int n_edges)
{
    __shared__ int lds[1024];
    int t = threadIdx.x;
    lds[t] = (t < nb) ? bsum[t] : 0;
    __syncthreads();
    for (int off = 1; off < 1024; off <<= 1) {
        int v = (t >= off) ? lds[t - off] : 0;
        __syncthreads();
        lds[t] += v;
        __syncthreads();
    }
    if (t < nb) boff[t] = (t == 0) ? 0 : lds[t - 1];
    if (t == 0) rowstart[n_nodes] = n_edges;
}

// ---------------- B3: apply block offsets -> rowstart, cursor ----------------
__global__ __launch_bounds__(256) void k_scan_apply(
    const int* __restrict__ local, const int* __restrict__ boff,
    int* __restrict__ rowstart, int* __restrict__ cursor, int n_nodes)
{
    int base = blockIdx.x * 1024 + threadIdx.x * 4;
    int off = boff[blockIdx.x];
    if (base + 3 < n_nodes) {
        int4 l = *(const int4*)&local[base];
        int4 r = make_int4(l.x + off, l.y + off, l.z + off, l.w + off);
        *(int4*)&rowstart[base] = r;
        *(int4*)&cursor[base] = r;
    } else {
        for (int i = 0; i < 4; ++i) {
            if (base + i < n_nodes) {
                int r = local[base + i] + off;
                rowstart[base + i] = r;
                cursor[base + i] = r;
            }
        }
    }
}

// ---------------- C: CSR fill, XCD-grouped to keep writes L2-resident --------
__global__ __launch_bounds__(256) void k_fill(
    const int* __restrict__ src, const int* __restrict__ dst,
    int* __restrict__ cursor, int* __restrict__ eidx, int n_edges, int n_nodes)
{
    int grp = blockIdx.x & (FILL_GRP - 1);
    int lo = (int)((long long)grp * n_nodes / FILL_GRP);
    int hi = (int)((long long)(grp + 1) * n_nodes / FILL_GRP);
    int nblk = gridDim.x >> 3;
    int bid = blockIdx.x >> 3;
    for (int e = bid * 256 + threadIdx.x; e < n_edges; e += nblk * 256) {
        int v = dst[e];
        if (v >= lo && v < hi) {
            int pos = atomicAdd(&cursor[v], 1);
            eidx[pos] = src[e];
        }
    }
}

// ---------------- D: layer-1 gather, quad-per-edge (4 edges/group) ----------
// featb rows = 16 dwords; quad q handles edge 4g+q, lane reads 1 dword
// (2 bf16 dims). Cross-quad shfl_xor reduce; quad 0 writes packed dword.
__global__ __launch_bounds__(256) void k_agg1(
    const int* __restrict__ rowstart, const int* __restrict__ eidx,
    const unsigned* __restrict__ fbd, const float* __restrict__ feat0,
    unsigned* __restrict__ hnbd, int n_nodes)
{
    int w = (int)((blockIdx.x * 256u + threadIdx.x) >> 6);
    int lane = threadIdx.x & 63;
    if (w >= n_nodes) return;
    int v = w;
    int quad = lane >> 4, l15 = lane & 15;
    int e0 = rowstart[v], e1 = rowstart[v + 1];
    int nedge = e1 - e0;
    float a0 = 0.f, a1 = 0.f;
    for (int base = 0; base < nedge; base += 64) {
        int cnt = min(64, nedge - base);
        int idx = 0;
        if (lane < cnt) idx = eidx[e0 + base + lane];
        int ngrp = (cnt + 3) >> 2;
#pragma unroll 8
        for (int g = 0; g < ngrp; ++g) {
            int sel = 4 * g + quad;
            bool val = sel < cnt;
            int s = __shfl(idx, min(sel, cnt - 1));
            unsigned u = fbd[(size_t)s * 16 + l15];
            u = val ? u : 0u;
            a0 += bf2f((unsigned short)(u & 0xFFFF));
            a1 += bf2f((unsigned short)(u >> 16));
        }
    }
    a0 += __shfl_xor(a0, 16); a0 += __shfl_xor(a0, 32);
    a1 += __shfl_xor(a1, 16); a1 += __shfl_xor(a1, 32);
    if (quad == 0) {
        int d0 = 2 * l15, d1 = 2 * l15 + 1;
        float f0 = (d0 < IN_DIM) ? feat0[(size_t)v * IN_DIM + d0] : 0.f;
        float f1 = (d1 < IN_DIM) ? feat0[(size_t)v * IN_DIM + d1] : 0.f;
        float inv = 1.0f / ((float)nedge + 1.0f);
        unsigned out = (unsigned)f2bf((a0 + f0) * inv)
                     | ((unsigned)f2bf((a1 + f1) * inv) << 16);
        hnbd[(size_t)v * 16 + l15] = out;
    }
}

// ---------------- E: MFMA node transform: m1 = relu(hn@W1+b1)/||.|| @ W2 -----
__global__ __launch_bounds__(256) void k_node(
    const unsigned short* __restrict__ hnb, const unsigned short* __restrict__ W1t,
    const float* __restrict__ b1, const unsigned short* __restrict__ W2t,
    unsigned short* __restrict__ m1, int n_nodes)
{
    __shared__ unsigned short ph[4][16 * PH_STRIDE];   // per-wave C->A transform
    int wave = threadIdx.x >> 6, lane = threadIdx.x & 63;
    int quad = lane >> 4, l15 = lane & 15;
    const f32x4 z4 = {0.f, 0.f, 0.f, 0.f};

    float bb[8];
#pragma unroll
    for (int t = 0; t < 8; ++t) bb[t] = b1[t * 16 + l15];

    for (int v0 = blockIdx.x * 64 + wave * 16; v0 < n_nodes; v0 += gridDim.x * 64) {
        bf16x8 aH = {0, 0, 0, 0, 0, 0, 0, 0};
        int vA = v0 + l15;
        if (vA < n_nodes) aH = *(const bf16x8*)&hnb[(size_t)vA * FB_DIM + quad * 8];
        f32x4 c1[8];
#pragma unroll
        for (int t = 0; t < 8; ++t) {
            bf16x8 bw = *(const bf16x8*)&W1t[(t * 16 + l15) * 32 + quad * 8];
            c1[t] = __builtin_amdgcn_mfma_f32_16x16x32_bf16(aH, bw, z4, 0, 0, 0);
        }
        float ssq[4] = {0.f, 0.f, 0.f, 0.f};
#pragma unroll
        for (int t = 0; t < 8; ++t) {
#pragma unroll
            for (int r = 0; r < 4; ++r) {
                float x = fmaxf(c1[t][r] + bb[t], 0.f);
                c1[t][r] = x;
                ssq[r] += x * x;
            }
        }
#pragma unroll
        for (int off = 1; off < 16; off <<= 1) {
#pragma unroll
            for (int r = 0; r < 4; ++r) ssq[r] += __shfl_xor(ssq[r], off);
        }
        float inv[4];
#pragma unroll
        for (int r = 0; r < 4; ++r) inv[r] = 1.0f / fmaxf(sqrtf(ssq[r]), 1e-12f);
#pragma unroll
        for (int t = 0; t < 8; ++t)
#pragma unroll
            for (int r = 0; r < 4; ++r)
                ph[wave][(quad * 4 + r) * PH_STRIDE + t * 16 + l15] =
                    f2bf(c1[t][r] * inv[r]);
        f32x4 c2[4] = {z4, z4, z4, z4};
#pragma unroll
        for (int ks = 0; ks < 4; ++ks) {
            bf16x8 aP = *(const bf16x8*)&ph[wave][l15 * PH_STRIDE + ks * 32 + quad * 8];
#pragma unroll
            for (int tn = 0; tn < 4; ++tn) {
                bf16x8 bw = *(const bf16x8*)&W2t[(tn * 16 + l15) * HID + ks * 32 + quad * 8];
                c2[tn] = __builtin_amdgcn_mfma_f32_16x16x32_bf16(aP, bw, c2[tn], 0, 0, 0);
            }
        }
#pragma unroll
        for (int tn = 0; tn < 4; ++tn)
#pragma unroll
            for (int r = 0; r < 4; ++r) {
                int v = v0 + quad * 4 + r;
                if (v < n_nodes) m1[(size_t)v * OUTD + tn * 16 + l15] = f2bf(c2[tn][r]);
            }
    }
}

// ---------------- E2: transcode m1 bf16 -> fp8 e4m3 (64B rows) ---------------
__global__ __launch_bounds__(256) void k_m1f8(
    const unsigned short* __restrict__ m1b, unsigned* __restrict__ m1f8,
    int n_dwords)
{
    int i = blockIdx.x * 256 + threadIdx.x;
    if (i >= n_dwords) return;
    const unsigned short* p = &m1b[(size_t)i * 4];
    unsigned c = enc_fp8(bf2f(p[0])) | (enc_fp8(bf2f(p[1])) << 8)
               | (enc_fp8(bf2f(p[2])) << 16) | (enc_fp8(bf2f(p[3])) << 24);
    m1f8[i] = c;
}

// ---------------- F: layer-2 gather (fp8, quad-per-edge) + graph mean --------
// m1f8 rows = 16 dwords; quad q handles edge 4g+q (32 edges in flight at
// unroll 8). Cross-quad reduce, self-term after, one LDS atomic per lane.
__global__ __launch_bounds__(256) void k_agg2g(
    const int* __restrict__ rowstart, const int* __restrict__ eidx,
    const unsigned* __restrict__ md, const int* __restrict__ gids,
    float* __restrict__ gpart, float* __restrict__ gcnt, int n_nodes)
{
    __shared__ float lsum[NGR * OUTD];
    __shared__ float lcnt[NGR];
    for (int i = threadIdx.x; i < NGR * OUTD; i += 256) lsum[i] = 0.f;
    if (threadIdx.x < NGR) lcnt[threadIdx.x] = 0.f;
    __syncthreads();

    int lane = threadIdx.x & 63;
    int quad = lane >> 4, l15 = lane & 15;
    int w = (int)((blockIdx.x * 256u + threadIdx.x) >> 6);
    int nw = (int)((gridDim.x * 256u) >> 6);
    for (int v = w; v < n_nodes; v += nw) {
        int e0 = rowstart[v], e1 = rowstart[v + 1];
        int nedge = e1 - e0;
        float a0 = 0.f, a1 = 0.f, a2 = 0.f, a3 = 0.f;
        for (int base = 0; base < nedge; base += 64) {
            int cnt = min(64, nedge - base);
            int idx = 0;
            if (lane < cnt) idx = eidx[e0 + base + lane];
            int ngrp = (cnt + 3) >> 2;
#pragma unroll 8
            for (int g = 0; g < ngrp; ++g) {
                int sel = 4 * g + quad;
                bool val = sel < cnt;
                int s = __shfl(idx, min(sel, cnt - 1));
                unsigned u = md[(size_t)s * 16 + l15];
                u = val ? u : 0u;
                float d0, d1, d2, d3;
                dec4_fp8(u, d0, d1, d2, d3);
                a0 += d0; a1 += d1; a2 += d2; a3 += d3;
            }
        }
        a0 += __shfl_xor(a0, 16); a0 += __shfl_xor(a0, 32);
        a1 += __shfl_xor(a1, 16); a1 += __shfl_xor(a1, 32);
        a2 += __shfl_xor(a2, 16); a2 += __shfl_xor(a2, 32);
        a3 += __shfl_xor(a3, 16); a3 += __shfl_xor(a3, 32);
        // self term (identical across quads; added once per quad's dim)
        {
            unsigned u = md[(size_t)v * 16 + l15];
            float d0, d1, d2, d3;
            dec4_fp8(u, d0, d1, d2, d3);
            a0 += d0; a1 += d1; a2 += d2; a3 += d3;
        }
        float inv = 1.0f / ((float)nedge + 1.0f);
        int g = gids[v];
        float mv = (quad == 0) ? a0 : (quad == 1) ? a1 : (quad == 2) ? a2 : a3;
        atomicAdd(&lsum[g * OUTD + 4 * l15 + quad], mv * inv);
        if (lane == 0) atomicAdd(&lcnt[g], 1.0f);
    }
    __syncthreads();
    float* gp = gpart + (size_t)(blockIdx.x & (NPART - 1)) * NGR * OUTD;
    for (int i = threadIdx.x; i < NGR * OUTD; i += 256) atomicAdd(&gp[i], lsum[i]);
    if (threadIdx.x < NGR) atomicAdd(&gcnt[threadIdx.x], lcnt[threadIdx.x]);
}

// ---------------- G: finalize: reduce partials, mean + b2 --------------------
__global__ __launch_bounds__(256) void k_final(
    const float* __restrict__ gpart, const float* __restrict__ gcnt,
    const float* __restrict__ b2, float* __restrict__ out)
{
    int i = blockIdx.x * 256 + threadIdx.x;
    if (i >= NGR * OUTD) return;
    int g = i >> 6, d = i & 63;
    float s = 0.f;
#pragma unroll
    for (int p = 0; p < NPART; ++p) s += gpart[(size_t)p * NGR * OUTD + i];
    float c = gcnt[g];
    out[i] = (c > 0.f) ? (s / c + b2[d]) : 0.f;
}

extern "C" void kernel_launch(void* const* d_in, const int* in_sizes, int n_in,
                              void* d_out, int out_size, void* d_ws, size_t ws_size,
                              hipStream_t stream) {
    const float* feat0 = (const float*)d_in[0];
    const float* W1    = (const float*)d_in[1];
    const float* b1    = (const float*)d_in[2];
    const float* W2    = (const float*)d_in[3];
    const float* b2    = (const float*)d_in[4];
    const int*   src   = (const int*)d_in[5];
    const int*   dst   = (const int*)d_in[6];
    const int*   gids  = (const int*)d_in[7];
    int n_edges = in_sizes[5];
    int n_nodes = in_sizes[7];

    int nb = (n_nodes + 1023) / 1024;   // scan blocks (98 for 100K nodes)

    // workspace: bf16 arrays (W1t|W2t|hnb) first (16B-aligned), then 4B arrays
    unsigned short* W1t = (unsigned short*)d_ws;
    unsigned short* W2t = W1t + HID * 32;
    unsigned short* hnb = W2t + (size_t)OUTD * HID;
    int*   degi     = (int*)(hnb + (size_t)n_nodes * FB_DIM);
    float* gpart    = (float*)(degi + n_nodes);
    float* gcnt     = gpart + (size_t)NPART * NGR * OUTD;
    int*   rowstart = (int*)(gcnt + NGR);
    int*   cursor   = rowstart + n_nodes + 1;
    int*   local    = cursor + n_nodes;
    int*   bsum     = local + n_nodes;
    int*   boff     = bsum + nb;
    int*   eidx     = boff + nb;
    unsigned* m1f8  = (unsigned*)(eidx + n_edges);
    unsigned short* featb = (unsigned short*)(m1f8 + (size_t)n_nodes * 16);
    unsigned short* m1b   = featb + (size_t)n_nodes * FB_DIM;

    size_t zero_units = (size_t)n_nodes + (size_t)NPART * NGR * OUTD + NGR;
    hipMemsetAsync(degi, 0, zero_units * 4, stream);

    unsigned blkE = (unsigned)((n_edges + 255) / 256);
    k_hist<<<blkE, 256, 0, stream>>>(dst, degi, n_edges);

    k_featb<<<(unsigned)(((long long)n_nodes * FB_DIM + 255) / 256), 256, 0, stream>>>(
        feat0, featb, n_nodes);
    k_wprep<<<(HID * 32 + OUTD * HID + 255) / 256, 256, 0, stream>>>(W1, W2, W1t, W2t);

    k_scan_local<<<nb, 256, 0, stream>>>(degi, local, bsum, n_nodes);
    k_scan_bsum<<<1, 1024, 0, stream>>>(bsum, boff, rowstart, nb, n_nodes, n_edges);
    k_scan_apply<<<nb, 256, 0, stream>>>(local, boff, rowstart, cursor, n_nodes);

    k_fill<<<2048, 256, 0, stream>>>(src, dst, cursor, eidx, n_edges, n_nodes);

    unsigned blkA = (unsigned)(((long long)n_nodes * 64 + 255) / 256);
    k_agg1<<<blkA, 256, 0, stream>>>(rowstart, eidx, (const unsigned*)featb, feat0,
                                     (unsigned*)hnb, n_nodes);

    k_node<<<1024, 256, 0, stream>>>(hnb, W1t, b1, W2t, m1b, n_nodes);

    int n_dwords = n_nodes * 16;
    k_m1f8<<<(n_dwords + 255) / 256, 256, 0, stream>>>(m1b, m1f8, n_dwords);

    k_agg2g<<<2048, 256, 0, stream>>>(rowstart, eidx, m1f8, gids, gpart, gcnt, n_nodes);

    k_final<<<(NGR * OUTD + 255) / 256, 256, 0, stream>>>(gpart, gcnt, b2, (float*)d_out);
}

// Round 9
// 365.281 us; speedup vs baseline: 1.0964x; 1.0964x over previous
//
#include <hip/hip_runtime.h>

#define IN_DIM 23
#define HID 128
#define OUTD 64
#define NGR 64
#define NPART 32
#define FILL_GRP 8
#define FB_DIM 32    // feat padded to 32 bf16 = 64B aligned rows
#define PH_STRIDE 136  // 16 rows x 136 bf16: 272B row stride (16B-aligned, bank-spread)

typedef __attribute__((ext_vector_type(8))) short bf16x8;
typedef __attribute__((ext_vector_type(4))) float f32x4;
typedef __attribute__((ext_vector_type(2))) float f32x2;

static __device__ __forceinline__ unsigned short f2bf(float x) {
    unsigned u = __float_as_uint(x);
    unsigned r = (u + 0x7FFFu + ((u >> 16) & 1u)) >> 16;   // RNE
    return (unsigned short)r;
}
static __device__ __forceinline__ float bf2f(unsigned short u) {
    return __uint_as_float((unsigned)u << 16);             // exact
}

// ---- fp8 e4m3 (OCP) encode: RNE, satfinite. Used only in transcode kernel. --
static __device__ __forceinline__ unsigned enc_fp8(float x) {
    float a = fabsf(x);
    unsigned s = (__float_as_uint(x) >> 31) << 7;
    if (!(a > 0.f)) return s;                    // zero
    a = fminf(a, 448.f);
    int eb; float fr = frexpf(a, &eb);           // a = fr*2^eb, fr in [0.5,1)
    int E = eb - 1;
    int code;
    if (E < -6) code = (int)rintf(ldexpf(a, 9)); // denormal path
    else        code = ((E + 7) << 3) + (int)rintf(ldexpf(fr, 4)) - 8;
    code = min(code, 0x7E);
    return s | (unsigned)code;
}

// ---- fp8 e4m3 decode: HW packed convert if available, exact manual fallback -
#if __has_builtin(__builtin_amdgcn_cvt_pk_f32_fp8)
static __device__ __forceinline__ void dec4_fp8(unsigned u, float& d0, float& d1,
                                                float& d2, float& d3) {
    f32x2 lo = __builtin_amdgcn_cvt_pk_f32_fp8((int)u, false);
    f32x2 hi = __builtin_amdgcn_cvt_pk_f32_fp8((int)u, true);
    d0 = lo[0]; d1 = lo[1]; d2 = hi[0]; d3 = hi[1];
}
#else
static __device__ __forceinline__ float dec1_fp8(unsigned b) {
    unsigned s = (b & 0x80u) << 24;
    unsigned em = b & 0x7Fu;
    float f = __uint_as_float(s | ((em << 20) + 0x3C000000u));
    if ((b & 0x78u) == 0)
        f = 2.f * f - __uint_as_float(s | 0x3C800000u);
    return f;
}
static __device__ __forceinline__ void dec4_fp8(unsigned u, float& d0, float& d1,
                                                float& d2, float& d3) {
    d0 = dec1_fp8(u & 0xFF); d1 = dec1_fp8((u >> 8) & 0xFF);
    d2 = dec1_fp8((u >> 16) & 0xFF); d3 = dec1_fp8(u >> 24);
}
#endif

// ---------------- A: int degree histogram ------------------------------------
__global__ __launch_bounds__(256) void k_hist(
    const int* __restrict__ dst, int* __restrict__ degi, int n_edges)
{
    int e = blockIdx.x * 256 + threadIdx.x;
    if (e < n_edges) atomicAdd(&degi[dst[e]], 1);
}

// ---------------- A2: transcode feat0 -> bf16 padded rows --------------------
__global__ __launch_bounds__(256) void k_featb(
    const float* __restrict__ feat0, unsigned short* __restrict__ featb,
    int n_nodes)
{
    int i = blockIdx.x * 256 + threadIdx.x;
    if (i >= n_nodes * FB_DIM) return;
    int v = i >> 5, d = i & (FB_DIM - 1);
    float x = (d < IN_DIM) ? feat0[(size_t)v * IN_DIM + d] : 0.f;
    featb[i] = f2bf(x);
}

// ---------------- A3: weight transpose+pad to bf16 MFMA B-operand layout -----
__global__ __launch_bounds__(256) void k_wprep(
    const float* __restrict__ W1, const float* __restrict__ W2,
    unsigned short* __restrict__ W1t, unsigned short* __restrict__ W2t)
{
    int i = blockIdx.x * 256 + threadIdx.x;
    if (i < HID * 32) {
        int h = i >> 5, d = i & 31;
        W1t[i] = f2bf((d < IN_DIM) ? W1[d * HID + h] : 0.f);
    } else if (i < HID * 32 + OUTD * HID) {
        int j = i - HID * 32;
        int o = j >> 7, k = j & 127;
        W2t[j] = f2bf(W2[k * OUTD + o]);
    }
}

// ---------------- B1: per-block local exclusive scan + block totals ----------
__global__ __launch_bounds__(256) void k_scan_local(
    const int* __restrict__ degi, int* __restrict__ local,
    int* __restrict__ bsum, int n_nodes)
{
    int base = blockIdx.x * 1024 + threadIdx.x * 4;
    int4 d = {0, 0, 0, 0};
    if (base + 3 < n_nodes) {
        d = *(const int4*)&degi[base];
    } else {
        if (base + 0 < n_nodes) d.x = degi[base + 0];
        if (base + 1 < n_nodes) d.y = degi[base + 1];
        if (base + 2 < n_nodes) d.z = degi[base + 2];
        if (base + 3 < n_nodes) d.w = degi[base + 3];
    }
    int tsum = d.x + d.y + d.z + d.w;
    int lane = threadIdx.x & 63;
    int wave = threadIdx.x >> 6;
    int s = tsum;
#pragma unroll
    for (int off = 1; off < 64; off <<= 1) {
        int v = __shfl_up(s, off);
        if (lane >= off) s += v;
    }
    __shared__ int wtot[4];
    if (lane == 63) wtot[wave] = s;
    __syncthreads();
    int woff = 0;
#pragma unroll
    for (int i = 0; i < 4; ++i) woff += (i < wave) ? wtot[i] : 0;
    int excl = woff + s - tsum;
    int l0 = excl;
    int l1 = l0 + d.x;
    int l2 = l1 + d.y;
    int l3 = l2 + d.z;
    if (base + 3 < n_nodes) {
        *(int4*)&local[base] = make_int4(l0, l1, l2, l3);
    } else {
        if (base + 0 < n_nodes) local[base + 0] = l0;
        if (base + 1 < n_nodes) local[base + 1] = l1;
        if (base + 2 < n_nodes) local[base + 2] = l2;
        if (base + 3 < n_nodes) local[base + 3] = l3;
    }
    if (threadIdx.x == 255) bsum[blockIdx.x] = excl + tsum;
}

// ---------------- B2: scan the (<=1024) block totals -------------------------
__global__ __launch_bounds__(1024) void k_scan_bsum(
    const int* __restrict__ bsum, int* __restrict__ boff,
    int* __restrict__ rowstart, int nb, int n_nodes, int n_edges)
{
    __shared__ int lds[1024];
    int t = threadIdx.x;
    lds[t] = (t < nb) ? bsum[t] : 0;
    __syncthreads();
    for (int off = 1; off < 1024; off <<= 1) {
        int v = (t >= off) ? lds[t - off] : 0;
        __syncthreads();
        lds[t] += v;
        __syncthreads();
    }
    if (t < nb) boff[t] = (t == 0) ? 0 : lds[t - 1];
    if (t == 0) rowstart[n_nodes] = n_edges;
}

// ---------------- B3: apply block offsets -> rowstart, cursor ----------------
__global__ __launch_bounds__(256) void k_scan_apply(
    const int* __restrict__ local, const int* __restrict__ boff,
    int* __restrict__ rowstart, int* __restrict__ cursor, int n_nodes)
{
    int base = blockIdx.x * 1024 + threadIdx.x * 4;
    int off = boff[blockIdx.x];
    if (base + 3 < n_nodes) {
        int4 l = *(const int4*)&local[base];
        int4 r = make_int4(l.x + off, l.y + off, l.z + off, l.w + off);
        *(int4*)&rowstart[base] = r;
        *(int4*)&cursor[base] = r;
    } else {
        for (int i = 0; i < 4; ++i) {
            if (base + i < n_nodes) {
                int r = local[base + i] + off;
                rowstart[base + i] = r;
                cursor[base + i] = r;
            }
        }
    }
}

// ---------------- C: CSR fill, XCD-grouped to keep writes L2-resident --------
__global__ __launch_bounds__(256) void k_fill(
    const int* __restrict__ src, const int* __restrict__ dst,
    int* __restrict__ cursor, int* __restrict__ eidx, int n_edges, int n_nodes)
{
    int grp = blockIdx.x & (FILL_GRP - 1);
    int lo = (int)((long long)grp * n_nodes / FILL_GRP);
    int hi = (int)((long long)(grp + 1) * n_nodes / FILL_GRP);
    int nblk = gridDim.x >> 3;
    int bid = blockIdx.x >> 3;
    for (int e = bid * 256 + threadIdx.x; e < n_edges; e += nblk * 256) {
        int v = dst[e];
        if (v >= lo && v < hi) {
            int pos = atomicAdd(&cursor[v], 1);
            eidx[pos] = src[e];
        }
    }
}

// ---------------- D: layer-1 gather, QUAD-PER-NODE ---------------------------
// Each 16-lane quad owns one node: 4 independent latency chains per wave.
// Quad loads 16 eidx at once; all <=16 row loads issued back-to-back
// (16 in flight/quad, 64/wave). Lane = 1 dword (2 bf16 dims); no reduce.
__global__ __launch_bounds__(256) void k_agg1(
    const int* __restrict__ rowstart, const int* __restrict__ eidx,
    const unsigned* __restrict__ fbd, const float* __restrict__ feat0,
    unsigned* __restrict__ hnbd, int n_nodes)
{
    int lane = threadIdx.x & 63;
    int quad = lane >> 4, l15 = lane & 15;
    int wglob = (int)((blockIdx.x * 256u + threadIdx.x) >> 6);
    int v = wglob * 4 + quad;
    if (v >= n_nodes) return;
    int e0 = rowstart[v], e1 = rowstart[v + 1];
    int nedge = e1 - e0;
    float a0 = 0.f, a1 = 0.f;
    for (int base = 0; base < nedge; base += 16) {
        int cnt = min(16, nedge - base);
        int idx = 0;
        if (l15 < cnt) idx = eidx[e0 + base + l15];
        unsigned uu[16];
#pragma unroll
        for (int j = 0; j < 16; ++j) {
            int s = __shfl(idx, quad * 16 + min(j, cnt - 1));
            uu[j] = 0u;
            if (j < cnt) uu[j] = fbd[(size_t)s * 16 + l15];
        }
#pragma unroll
        for (int j = 0; j < 16; ++j) {
            a0 += bf2f((unsigned short)(uu[j] & 0xFFFF));
            a1 += bf2f((unsigned short)(uu[j] >> 16));
        }
    }
    int d0 = 2 * l15, d1 = d0 + 1;
    float f0 = (d0 < IN_DIM) ? feat0[(size_t)v * IN_DIM + d0] : 0.f;
    float f1 = (d1 < IN_DIM) ? feat0[(size_t)v * IN_DIM + d1] : 0.f;
    float inv = 1.0f / ((float)nedge + 1.0f);
    unsigned out = (unsigned)f2bf((a0 + f0) * inv)
                 | ((unsigned)f2bf((a1 + f1) * inv) << 16);
    hnbd[(size_t)v * 16 + l15] = out;
}

// ---------------- E: MFMA node transform: m1 = relu(hn@W1+b1)/||.|| @ W2 -----
__global__ __launch_bounds__(256) void k_node(
    const unsigned short* __restrict__ hnb, const unsigned short* __restrict__ W1t,
    const float* __restrict__ b1, const unsigned short* __restrict__ W2t,
    unsigned short* __restrict__ m1, int n_nodes)
{
    __shared__ unsigned short ph[4][16 * PH_STRIDE];   // per-wave C->A transform
    int wave = threadIdx.x >> 6, lane = threadIdx.x & 63;
    int quad = lane >> 4, l15 = lane & 15;
    const f32x4 z4 = {0.f, 0.f, 0.f, 0.f};

    float bb[8];
#pragma unroll
    for (int t = 0; t < 8; ++t) bb[t] = b1[t * 16 + l15];

    for (int v0 = blockIdx.x * 64 + wave * 16; v0 < n_nodes; v0 += gridDim.x * 64) {
        bf16x8 aH = {0, 0, 0, 0, 0, 0, 0, 0};
        int vA = v0 + l15;
        if (vA < n_nodes) aH = *(const bf16x8*)&hnb[(size_t)vA * FB_DIM + quad * 8];
        f32x4 c1[8];
#pragma unroll
        for (int t = 0; t < 8; ++t) {
            bf16x8 bw = *(const bf16x8*)&W1t[(t * 16 + l15) * 32 + quad * 8];
            c1[t] = __builtin_amdgcn_mfma_f32_16x16x32_bf16(aH, bw, z4, 0, 0, 0);
        }
        float ssq[4] = {0.f, 0.f, 0.f, 0.f};
#pragma unroll
        for (int t = 0; t < 8; ++t) {
#pragma unroll
            for (int r = 0; r < 4; ++r) {
                float x = fmaxf(c1[t][r] + bb[t], 0.f);
                c1[t][r] = x;
                ssq[r] += x * x;
            }
        }
#pragma unroll
        for (int off = 1; off < 16; off <<= 1) {
#pragma unroll
            for (int r = 0; r < 4; ++r) ssq[r] += __shfl_xor(ssq[r], off);
        }
        float inv[4];
#pragma unroll
        for (int r = 0; r < 4; ++r) inv[r] = 1.0f / fmaxf(sqrtf(ssq[r]), 1e-12f);
#pragma unroll
        for (int t = 0; t < 8; ++t)
#pragma unroll
            for (int r = 0; r < 4; ++r)
                ph[wave][(quad * 4 + r) * PH_STRIDE + t * 16 + l15] =
                    f2bf(c1[t][r] * inv[r]);
        f32x4 c2[4] = {z4, z4, z4, z4};
#pragma unroll
        for (int ks = 0; ks < 4; ++ks) {
            bf16x8 aP = *(const bf16x8*)&ph[wave][l15 * PH_STRIDE + ks * 32 + quad * 8];
#pragma unroll
            for (int tn = 0; tn < 4; ++tn) {
                bf16x8 bw = *(const bf16x8*)&W2t[(tn * 16 + l15) * HID + ks * 32 + quad * 8];
                c2[tn] = __builtin_amdgcn_mfma_f32_16x16x32_bf16(aP, bw, c2[tn], 0, 0, 0);
            }
        }
#pragma unroll
        for (int tn = 0; tn < 4; ++tn)
#pragma unroll
            for (int r = 0; r < 4; ++r) {
                int v = v0 + quad * 4 + r;
                if (v < n_nodes) m1[(size_t)v * OUTD + tn * 16 + l15] = f2bf(c2[tn][r]);
            }
    }
}

// ---------------- E2: transcode m1 bf16 -> fp8 e4m3 (64B rows) ---------------
__global__ __launch_bounds__(256) void k_m1f8(
    const unsigned short* __restrict__ m1b, unsigned* __restrict__ m1f8,
    int n_dwords)
{
    int i = blockIdx.x * 256 + threadIdx.x;
    if (i >= n_dwords) return;
    const unsigned short* p = &m1b[(size_t)i * 4];
    unsigned c = enc_fp8(bf2f(p[0])) | (enc_fp8(bf2f(p[1])) << 8)
               | (enc_fp8(bf2f(p[2])) << 16) | (enc_fp8(bf2f(p[3])) << 24);
    m1f8[i] = c;
}

// ---------------- F: layer-2 gather, QUAD-PER-NODE (fp8) + graph mean --------
// 4 independent per-node chains per wave; 16 row loads in flight per quad.
// Lane holds dims 4*l15..+3 of its quad's node; no cross-lane reduce.
__global__ __launch_bounds__(256) void k_agg2g(
    const int* __restrict__ rowstart, const int* __restrict__ eidx,
    const unsigned* __restrict__ md, const int* __restrict__ gids,
    float* __restrict__ gpart, float* __restrict__ gcnt, int n_nodes)
{
    __shared__ float lsum[NGR * OUTD];
    __shared__ float lcnt[NGR];
    for (int i = threadIdx.x; i < NGR * OUTD; i += 256) lsum[i] = 0.f;
    if (threadIdx.x < NGR) lcnt[threadIdx.x] = 0.f;
    __syncthreads();

    int lane = threadIdx.x & 63;
    int quad = lane >> 4, l15 = lane & 15;
    int wglob = (int)((blockIdx.x * 256u + threadIdx.x) >> 6);
    int nw = (int)((gridDim.x * 256u) >> 6);
    for (int v = wglob * 4 + quad; v < n_nodes; v += nw * 4) {
        int e0 = rowstart[v], e1 = rowstart[v + 1];
        int nedge = e1 - e0;
        float a0 = 0.f, a1 = 0.f, a2 = 0.f, a3 = 0.f;
        for (int base = 0; base < nedge; base += 16) {
            int cnt = min(16, nedge - base);
            int idx = 0;
            if (l15 < cnt) idx = eidx[e0 + base + l15];
            unsigned uu[16];
#pragma unroll
            for (int j = 0; j < 16; ++j) {
                int s = __shfl(idx, quad * 16 + min(j, cnt - 1));
                uu[j] = 0u;
                if (j < cnt) uu[j] = md[(size_t)s * 16 + l15];
            }
#pragma unroll
            for (int j = 0; j < 16; ++j) {
                float d0, d1, d2, d3;
                dec4_fp8(uu[j], d0, d1, d2, d3);
                a0 += d0; a1 += d1; a2 += d2; a3 += d3;
            }
        }
        // self term
        {
            unsigned u = md[(size_t)v * 16 + l15];
            float d0, d1, d2, d3;
            dec4_fp8(u, d0, d1, d2, d3);
            a0 += d0; a1 += d1; a2 += d2; a3 += d3;
        }
        float inv = 1.0f / ((float)nedge + 1.0f);
        int g = gids[v];
        atomicAdd(&lsum[g * OUTD + 4 * l15 + 0], a0 * inv);
        atomicAdd(&lsum[g * OUTD + 4 * l15 + 1], a1 * inv);
        atomicAdd(&lsum[g * OUTD + 4 * l15 + 2], a2 * inv);
        atomicAdd(&lsum[g * OUTD + 4 * l15 + 3], a3 * inv);
        if (l15 == 0) atomicAdd(&lcnt[g], 1.0f);
    }
    __syncthreads();
    float* gp = gpart + (size_t)(blockIdx.x & (NPART - 1)) * NGR * OUTD;
    for (int i = threadIdx.x; i < NGR * OUTD; i += 256) atomicAdd(&gp[i], lsum[i]);
    if (threadIdx.x < NGR) atomicAdd(&gcnt[threadIdx.x], lcnt[threadIdx.x]);
}

// ---------------- G: finalize: reduce partials, mean + b2 --------------------
__global__ __launch_bounds__(256) void k_final(
    const float* __restrict__ gpart, const float* __restrict__ gcnt,
    const float* __restrict__ b2, float* __restrict__ out)
{
    int i = blockIdx.x * 256 + threadIdx.x;
    if (i >= NGR * OUTD) return;
    int g = i >> 6, d = i & 63;
    float s = 0.f;
#pragma unroll
    for (int p = 0; p < NPART; ++p) s += gpart[(size_t)p * NGR * OUTD + i];
    float c = gcnt[g];
    out[i] = (c > 0.f) ? (s / c + b2[d]) : 0.f;
}

extern "C" void kernel_launch(void* const* d_in, const int* in_sizes, int n_in,
                              void* d_out, int out_size, void* d_ws, size_t ws_size,
                              hipStream_t stream) {
    const float* feat0 = (const float*)d_in[0];
    const float* W1    = (const float*)d_in[1];
    const float* b1    = (const float*)d_in[2];
    const float* W2    = (const float*)d_in[3];
    const float* b2    = (const float*)d_in[4];
    const int*   src   = (const int*)d_in[5];
    const int*   dst   = (const int*)d_in[6];
    const int*   gids  = (const int*)d_in[7];
    int n_edges = in_sizes[5];
    int n_nodes = in_sizes[7];

    int nb = (n_nodes + 1023) / 1024;   // scan blocks (98 for 100K nodes)

    // workspace: bf16 arrays (W1t|W2t|hnb) first (16B-aligned), then 4B arrays
    unsigned short* W1t = (unsigned short*)d_ws;
    unsigned short* W2t = W1t + HID * 32;
    unsigned short* hnb = W2t + (size_t)OUTD * HID;
    int*   degi     = (int*)(hnb + (size_t)n_nodes * FB_DIM);
    float* gpart    = (float*)(degi + n_nodes);
    float* gcnt     = gpart + (size_t)NPART * NGR * OUTD;
    int*   rowstart = (int*)(gcnt + NGR);
    int*   cursor   = rowstart + n_nodes + 1;
    int*   local    = cursor + n_nodes;
    int*   bsum     = local + n_nodes;
    int*   boff     = bsum + nb;
    int*   eidx     = boff + nb;
    unsigned* m1f8  = (unsigned*)(eidx + n_edges);
    unsigned short* featb = (unsigned short*)(m1f8 + (size_t)n_nodes * 16);
    unsigned short* m1b   = featb + (size_t)n_nodes * FB_DIM;

    size_t zero_units = (size_t)n_nodes + (size_t)NPART * NGR * OUTD + NGR;
    hipMemsetAsync(degi, 0, zero_units * 4, stream);

    unsigned blkE = (unsigned)((n_edges + 255) / 256);
    k_hist<<<blkE, 256, 0, stream>>>(dst, degi, n_edges);

    k_featb<<<(unsigned)(((long long)n_nodes * FB_DIM + 255) / 256), 256, 0, stream>>>(
        feat0, featb, n_nodes);
    k_wprep<<<(HID * 32 + OUTD * HID + 255) / 256, 256, 0, stream>>>(W1, W2, W1t, W2t);

    k_scan_local<<<nb, 256, 0, stream>>>(degi, local, bsum, n_nodes);
    k_scan_bsum<<<1, 1024, 0, stream>>>(bsum, boff, rowstart, nb, n_nodes, n_edges);
    k_scan_apply<<<nb, 256, 0, stream>>>(local, boff, rowstart, cursor, n_nodes);

    k_fill<<<2048, 256, 0, stream>>>(src, dst, cursor, eidx, n_edges, n_nodes);

    // quad-per-node: 16 nodes per 256-thread block
    unsigned blkA = (unsigned)((n_nodes + 15) / 16);
    k_agg1<<<blkA, 256, 0, stream>>>(rowstart, eidx, (const unsigned*)featb, feat0,
                                     (unsigned*)hnb, n_nodes);

    k_node<<<1024, 256, 0, stream>>>(hnb, W1t, b1, W2t, m1b, n_nodes);

    int n_dwords = n_nodes * 16;
    k_m1f8<<<(n_dwords + 255) / 256, 256, 0, stream>>>(m1b, m1f8, n_dwords);

    k_agg2g<<<2048, 256, 0, stream>>>(rowstart, eidx, m1f8, gids, gpart, gcnt, n_nodes);

    k_final<<<(NGR * OUTD + 255) / 256, 256, 0, stream>>>(gpart, gcnt, b2, (float*)d_out);
}